// Round 2
// baseline (162.792 us; speedup 1.0000x reference)
//
#include <hip/hip_runtime.h>
#include <hip/hip_bf16.h>

#define B_   2
#define S_   1024
#define E_   2048
#define NH_  16
#define DH_  128
#define EPS_ 1e-6f

using half8   = __attribute__((ext_vector_type(8))) _Float16;
using floatx4 = __attribute__((ext_vector_type(4))) float;

__device__ __forceinline__ half8 cvt8h(const float* __restrict__ p) {
    float4 a = *(const float4*)p;
    float4 b = *(const float4*)(p + 4);
    half8 r;
    r[0] = (_Float16)a.x; r[1] = (_Float16)a.y;
    r[2] = (_Float16)a.z; r[3] = (_Float16)a.w;
    r[4] = (_Float16)b.x; r[5] = (_Float16)b.y;
    r[6] = (_Float16)b.z; r[7] = (_Float16)b.w;
    return r;
}

// ---------------------------------------------------------------------------
// Kernel 1: gate GEMM (K-split x8, disjoint partial buffers) FUSED with the
// f16 pre-conversion of q,k (direct) and v (LDS transpose -> [bh][d][s]).
// ---------------------------------------------------------------------------
__global__ __launch_bounds__(256, 4) void gates_kernel(
    const float* __restrict__ q, const float* __restrict__ k,
    const float* __restrict__ v, const float* __restrict__ Wi,
    const float* __restrict__ Wf, float* __restrict__ pre_i,
    float* __restrict__ pre_f, _Float16* __restrict__ qhg,
    _Float16* __restrict__ khg, _Float16* __restrict__ vtg)
{
    __shared__ __attribute__((aligned(16))) _Float16 xs[32 * 264];
    __shared__ __attribute__((aligned(16))) _Float16 wt[32 * 264];

    const int t    = threadIdx.x;
    const int w    = t >> 6, lane = t & 63, quad = lane >> 4, l15 = lane & 15;
    const int mw   = w & 1, nw = w >> 1;
    const int m0   = blockIdx.x * 32;
    const int by   = blockIdx.y;
    const int kbase = by * 768;
    const int bblk = m0 >> 10;           // batch index (constant per block)
    const int s0   = m0 & 1023;

    floatx4 acc = {0.f, 0.f, 0.f, 0.f};

    for (int c = 0; c < 3; ++c) {
        __syncthreads();
        const int e0   = kbase + c * 256;
        const int tsel = e0 >> 11;            // 0:q 1:k 2:v
        const int el0  = e0 & 2047;
        const float* xb = (tsel == 0) ? q : (tsel == 1) ? k : v;
        _Float16* fout = (tsel == 0) ? qhg : khg;   // direct f16 emit (q/k)
        #pragma unroll
        for (int i = 0; i < 4; ++i) {
            int g = t + i * 256;
            int row = g >> 5, grp = g & 31;
            half8 s8 = cvt8h(xb + (size_t)(m0 + row) * E_ + el0 + grp * 8);
            *(half8*)(&xs[row * 264 + grp * 8]) = s8;
            if (tsel < 2) {
                int el = el0 + grp * 8;
                int h  = el >> 7, d = el & 127;
                *(half8*)(fout + ((size_t)(bblk * NH_ + h) * S_ + s0 + row) * DH_ + d) = s8;
            }
        }
        {
            const int kk = t;
            const float* wiRow = Wi + (size_t)(e0 + kk) * NH_;
            const float* wfRow = Wf + (size_t)(e0 + kk) * NH_;
            float wif[16], wff[16];
            #pragma unroll
            for (int i4 = 0; i4 < 4; ++i4) {
                float4 a = *(const float4*)(wiRow + i4 * 4);
                wif[i4*4+0]=a.x; wif[i4*4+1]=a.y; wif[i4*4+2]=a.z; wif[i4*4+3]=a.w;
                float4 b = *(const float4*)(wfRow + i4 * 4);
                wff[i4*4+0]=b.x; wff[i4*4+1]=b.y; wff[i4*4+2]=b.z; wff[i4*4+3]=b.w;
            }
            #pragma unroll
            for (int hh = 0; hh < 16; ++hh) wt[hh * 264 + kk]        = (_Float16)wif[hh];
            #pragma unroll
            for (int hh = 0; hh < 16; ++hh) wt[(16 + hh) * 264 + kk] = (_Float16)wff[hh];
        }
        __syncthreads();
        // v chunk: emit transposed f16 [bh][d][s] from the staged LDS tile.
        if (tsel == 2) {
            const int col = t;                       // 0..255
            const int el  = el0 + col;
            const int h   = el >> 7, d = el & 127;
            _Float16 tmp[32];
            #pragma unroll
            for (int r = 0; r < 32; ++r) tmp[r] = xs[r * 264 + col];
            const size_t vo = ((size_t)(bblk * NH_ + h) * DH_ + d) * S_ + s0;
            #pragma unroll
            for (int i = 0; i < 4; ++i)
                *(half8*)(vtg + vo + i * 8) = *(half8*)(&tmp[i * 8]);
        }
        #pragma unroll
        for (int ks = 0; ks < 8; ++ks) {
            half8 af = *(const half8*)(&xs[(mw * 16 + l15) * 264 + ks * 32 + quad * 8]);
            half8 bw = *(const half8*)(&wt[(nw * 16 + l15) * 264 + ks * 32 + quad * 8]);
            acc = __builtin_amdgcn_mfma_f32_16x16x32_f16(af, bw, acc, 0, 0, 0);
        }
    }
    #pragma unroll
    for (int reg = 0; reg < 4; ++reg) {
        int m   = m0 + mw * 16 + quad * 4 + reg;
        int b   = m >> 10, s = m & 1023;
        int col = nw * 16 + l15;
        float vacc = acc[reg];
        if (col < 16)
            pre_i[((size_t)(by * 32 + b * NH_ + col)) * S_ + s] = vacc;
        else
            pre_f[((size_t)(by * 32 + b * NH_ + col - 16)) * S_ + s] = vacc;
    }
}

// ---------------------------------------------------------------------------
// Kernel 2: two-level block-parallel scan.
// ---------------------------------------------------------------------------
__global__ __launch_bounds__(1024, 1) void scan_kernel(
    const float* __restrict__ pre_i, const float* __restrict__ pre_f,
    float* __restrict__ Aj, float* __restrict__ Cq,
    float* __restrict__ NFo, const float* __restrict__ bi,
    const float* __restrict__ bfb)
{
    __shared__ float wsumF[16], wmaxA[16];
    const int bh   = blockIdx.x;
    const int h    = bh & 15;
    const int t    = threadIdx.x;        // = s
    const int lane = t & 63, wv = t >> 6;

    float igv = bi[h], x = bfb[h];
    #pragma unroll
    for (int y = 0; y < 8; ++y) {
        igv += pre_i[((size_t)(y * 32 + bh)) * S_ + t];
        x   += pre_f[((size_t)(y * 32 + bh)) * S_ + t];
    }
    float lfv = (x >= 0.f) ? -log1pf(__expf(-x)) : (x - log1pf(__expf(x)));

    float sc = lfv;
    #pragma unroll
    for (int off = 1; off < 64; off <<= 1) {
        float o = __shfl_up(sc, off);
        if (lane >= off) sc += o;
    }
    if (lane == 63) wsumF[wv] = sc;
    __syncthreads();
    float Foff = 0.f;
    for (int i = 0; i < wv; ++i) Foff += wsumF[i];
    float F = Foff + sc;
    float a = igv - F;

    float ms = a;
    #pragma unroll
    for (int off = 1; off < 64; off <<= 1) {
        float o = __shfl_up(ms, off);
        if (lane >= off) ms = fmaxf(ms, o);
    }
    if (lane == 63) wmaxA[wv] = ms;
    __syncthreads();
    float Moff = -3.0e38f;
    for (int i = 0; i < wv; ++i) Moff = fmaxf(Moff, wmaxA[i]);
    float M = fmaxf(Moff, ms);

    size_t o = (size_t)bh * S_ + t;
    Aj[o]  = a;
    Cq[o]  = -M;
    NFo[o] = expf(fminf(-(F + M), 80.f));
}

// ---------------------------------------------------------------------------
// Kernel 3: fused causal attention. Each block handles TWO 64-row q-tiles
// (qa=qpi, qb=15-qpi) of one (b,h); waves 0,1 own qa (32 rows each), waves
// 2,3 own qb. K/V tiles staged once serve both tiles; each wave owns 32 q
// rows so every bk/bv LDS read feeds TWO MFMAs (2x fragment reuse).
// Work per block is constant (17 tile-computations) -> balanced grid of 256.
// ---------------------------------------------------------------------------
__global__ __launch_bounds__(256, 1) void attn_kernel(
    const _Float16* __restrict__ qh, const _Float16* __restrict__ kh,
    const _Float16* __restrict__ vtg, const float* __restrict__ Aj,
    const float* __restrict__ Cq, const float* __restrict__ NFi,
    const float* __restrict__ lnsc, float* __restrict__ out)
{
    __shared__ __attribute__((aligned(16))) _Float16 Ks[64 * 136];
    __shared__ __attribute__((aligned(16))) _Float16 Vt[128 * 72];
    __shared__ __attribute__((aligned(16))) _Float16 Pb[128 * 72];
    __shared__ float aj[64];

    const int t    = threadIdx.x;
    const int w    = t >> 6, lane = t & 63, quad = lane >> 4, l15 = lane & 15;
    const int bid  = blockIdx.x;
    const int bh   = bid & 31;           // bid%8 == bh%8 -> 4 bh per XCD (L2 reuse)
    const int qpi  = bid >> 5;           // 0..7
    const int b    = bh >> 4, h = bh & 15;
    const int myq  = (w < 2) ? qpi : (15 - qpi);  // this wave's q-tile index
    const int ktN  = 15 - qpi;                    // last k-tile staged by block
    const int qrow0 = myq * 64 + (w & 1) * 32;    // wave's first global q row
    const int prow0 = w * 32;                     // wave's Pb row base
    const int krow = t >> 2, kd0 = (t & 3) * 32;  // K staging: 4 x b128
    const int vd   = t >> 1, vj0 = (t & 1) * 32;  // V staging: 4 x b128

    float ci_r[2][4], nfv_r[2][4];
    #pragma unroll
    for (int s = 0; s < 2; ++s)
        #pragma unroll
        for (int reg = 0; reg < 4; ++reg) {
            int rl = qrow0 + s * 16 + quad * 4 + reg;
            ci_r[s][reg]  = Cq[(size_t)bh * S_ + rl];
            nfv_r[s][reg] = NFi[(size_t)bh * S_ + rl];
        }
    half8 aq[2][4];
    #pragma unroll
    for (int s = 0; s < 2; ++s) {
        const _Float16* qrow = qh + ((size_t)bh * S_ + qrow0 + s * 16 + l15) * DH_;
        #pragma unroll
        for (int ks = 0; ks < 4; ++ks)
            aq[s][ks] = *(const half8*)(qrow + ks * 32 + quad * 8);
    }

    // ---- prefetch tile 0 ----
    half8 kreg[4], vreg[4];
    float ajreg = 0.f;
    {
        const _Float16* kp = kh + ((size_t)bh * S_ + krow) * DH_ + kd0;
        const _Float16* vp = vtg + ((size_t)bh * DH_ + vd) * S_ + vj0;
        #pragma unroll
        for (int i = 0; i < 4; ++i) { kreg[i] = *(const half8*)(kp + i * 8);
                                      vreg[i] = *(const half8*)(vp + i * 8); }
    }
    if (t < 64) ajreg = Aj[(size_t)bh * S_ + t];

    #pragma unroll
    for (int i = 0; i < 4; ++i) {
        *(half8*)(&Ks[krow * 136 + kd0 + i * 8]) = kreg[i];
        *(half8*)(&Vt[vd * 72 + vj0 + i * 8])    = vreg[i];
    }
    if (t < 64) aj[t] = ajreg;
    __syncthreads();

    floatx4 acc_h[2][8];
    #pragma unroll
    for (int s = 0; s < 2; ++s)
        #pragma unroll
        for (int i = 0; i < 8; ++i) acc_h[s][i] = (floatx4){0.f, 0.f, 0.f, 0.f};
    float lrun[2][4] = {{0.f, 0.f, 0.f, 0.f}, {0.f, 0.f, 0.f, 0.f}};
    const float rscale = 0.08838834764831845f;   // 1/sqrt(128)

    for (int kt = 0; kt <= ktN; ++kt) {
        if (kt < ktN) {
            const int j0n = (kt + 1) * 64;
            const _Float16* kp = kh + ((size_t)bh * S_ + j0n + krow) * DH_ + kd0;
            const _Float16* vp = vtg + ((size_t)bh * DH_ + vd) * S_ + j0n + vj0;
            #pragma unroll
            for (int i = 0; i < 4; ++i) { kreg[i] = *(const half8*)(kp + i * 8);
                                          vreg[i] = *(const half8*)(vp + i * 8); }
            if (t < 64) ajreg = Aj[(size_t)bh * S_ + j0n + t];
        }

        if (kt <= myq) {
            // ---- QK: 16 bk reads feed 32 MFMAs (2 q-slices) ----
            floatx4 sacc[2][4];
            #pragma unroll
            for (int s = 0; s < 2; ++s)
                #pragma unroll
                for (int nt = 0; nt < 4; ++nt) sacc[s][nt] = (floatx4){0.f, 0.f, 0.f, 0.f};
            #pragma unroll
            for (int ks = 0; ks < 4; ++ks) {
                #pragma unroll
                for (int nt = 0; nt < 4; ++nt) {
                    half8 bk = *(const half8*)(&Ks[(nt * 16 + l15) * 136 + ks * 32 + quad * 8]);
                    sacc[0][nt] = __builtin_amdgcn_mfma_f32_16x16x32_f16(aq[0][ks], bk, sacc[0][nt], 0, 0, 0);
                    sacc[1][nt] = __builtin_amdgcn_mfma_f32_16x16x32_f16(aq[1][ks], bk, sacc[1][nt], 0, 0, 0);
                }
            }
            const bool diag = (kt == myq);
            #pragma unroll
            for (int nt = 0; nt < 4; ++nt) {
                int jl = nt * 16 + l15;
                float a_j = aj[jl];
                #pragma unroll
                for (int s = 0; s < 2; ++s) {
                    #pragma unroll
                    for (int reg = 0; reg < 4; ++reg) {
                        int rloc = (w & 1) * 32 + s * 16 + quad * 4 + reg;  // row local in 64-tile
                        float p = 0.f;
                        if (!diag || (jl <= rloc))
                            p = sacc[s][nt][reg] * rscale * __expf(fminf(ci_r[s][reg] + a_j, 0.f));
                        lrun[s][reg] += p;
                        Pb[(prow0 + s * 16 + quad * 4 + reg) * 72 + jl] = (_Float16)p;
                    }
                }
            }
            // ---- PV: 16 bv reads feed 32 MFMAs ----
            #pragma unroll
            for (int ks2 = 0; ks2 < 2; ++ks2) {
                half8 ap0 = *(const half8*)(&Pb[(prow0 + l15) * 72 + ks2 * 32 + quad * 8]);
                half8 ap1 = *(const half8*)(&Pb[(prow0 + 16 + l15) * 72 + ks2 * 32 + quad * 8]);
                #pragma unroll
                for (int nt2 = 0; nt2 < 8; ++nt2) {
                    half8 bv = *(const half8*)(&Vt[(nt2 * 16 + l15) * 72 + ks2 * 32 + quad * 8]);
                    acc_h[0][nt2] = __builtin_amdgcn_mfma_f32_16x16x32_f16(ap0, bv, acc_h[0][nt2], 0, 0, 0);
                    acc_h[1][nt2] = __builtin_amdgcn_mfma_f32_16x16x32_f16(ap1, bv, acc_h[1][nt2], 0, 0, 0);
                }
            }
        }

        __syncthreads();   // b1: all LDS reads of tile kt complete
        if (kt < ktN) {
            #pragma unroll
            for (int i = 0; i < 4; ++i) {
                *(half8*)(&Ks[krow * 136 + kd0 + i * 8]) = kreg[i];
                *(half8*)(&Vt[vd * 72 + vj0 + i * 8])    = vreg[i];
            }
            if (t < 64) aj[t] = ajreg;
            __syncthreads();   // b2: tile kt+1 staged
        }
    }

    // epilogue: normalizer + per-head LayerNorm over DH (per q-slice s)
    #pragma unroll
    for (int s = 0; s < 2; ++s) {
        #pragma unroll
        for (int reg = 0; reg < 4; ++reg) {
            float l = lrun[s][reg];
            #pragma unroll
            for (int off = 1; off < 16; off <<= 1) l += __shfl_xor(l, off);
            int rl = qrow0 + s * 16 + quad * 4 + reg;
            float nrm = fmaxf(fabsf(l), nfv_r[s][reg]) + EPS_;
            float inv = 1.f / nrm;
            float hv[8];
            float sum = 0.f, sq = 0.f;
            #pragma unroll
            for (int nt2 = 0; nt2 < 8; ++nt2) {
                float x = acc_h[s][nt2][reg] * inv;
                hv[nt2] = x; sum += x; sq += x * x;
            }
            #pragma unroll
            for (int off = 1; off < 16; off <<= 1) {
                sum += __shfl_xor(sum, off);
                sq  += __shfl_xor(sq, off);
            }
            float mean = sum * (1.f / 128.f);
            float var  = fmaxf(sq * (1.f / 128.f) - mean * mean, 0.f);
            float rstd = rsqrtf(var + EPS_);
            size_t orow = ((size_t)b * S_ + rl) * E_ + h * DH_;
            #pragma unroll
            for (int nt2 = 0; nt2 < 8; ++nt2) {
                int d = nt2 * 16 + l15;
                out[orow + d] = (hv[nt2] - mean) * rstd * lnsc[h * DH_ + d];
            }
        }
    }
}

// ---------------------------------------------------------------------------
extern "C" void kernel_launch(void* const* d_in, const int* in_sizes, int n_in,
                              void* d_out, int out_size, void* d_ws, size_t ws_size,
                              hipStream_t stream)
{
    const float* q    = (const float*)d_in[0];
    const float* k    = (const float*)d_in[1];
    const float* v    = (const float*)d_in[2];
    const float* Wi   = (const float*)d_in[3];
    const float* bi   = (const float*)d_in[4];
    const float* Wf   = (const float*)d_in[5];
    const float* bfb  = (const float*)d_in[6];
    const float* lnsc = (const float*)d_in[7];
    float* out        = (float*)d_out;

    const int NS  = B_ * NH_ * S_;       // 32768
    float* pre_i = (float*)d_ws;         // [8][32][1024] partials
    float* pre_f = pre_i + 8 * NS;
    float* Aj    = pre_f + 8 * NS;
    float* Cq    = Aj + NS;
    float* NFa   = Cq + NS;
    _Float16* qh  = (_Float16*)(NFa + NS);          // [32][1024][128] f16
    _Float16* kh  = qh + (size_t)32 * S_ * DH_;
    _Float16* vtg = kh + (size_t)32 * S_ * DH_;     // [32][128][1024] f16

    gates_kernel<<<dim3(64, 8), 256, 0, stream>>>(q, k, v, Wi, Wf, pre_i, pre_f,
                                                  qh, kh, vtg);
    scan_kernel<<<dim3(32), 1024, 0, stream>>>(pre_i, pre_f, Aj, Cq, NFa, bi, bfb);
    attn_kernel<<<dim3(256), 256, 0, stream>>>(qh, kh, vtg, Aj, Cq, NFa, lnsc, out);
}

// Round 3
// 145.564 us; speedup vs baseline: 1.1184x; 1.1184x over previous
//
#include <hip/hip_runtime.h>
#include <hip/hip_bf16.h>

#define B_   2
#define S_   1024
#define E_   2048
#define NH_  16
#define DH_  128
#define EPS_ 1e-6f

using half8   = __attribute__((ext_vector_type(8))) _Float16;
using floatx4 = __attribute__((ext_vector_type(4))) float;

__device__ __forceinline__ half8 cvt8h(const float* __restrict__ p) {
    float4 a = *(const float4*)p;
    float4 b = *(const float4*)(p + 4);
    half8 r;
    r[0] = (_Float16)a.x; r[1] = (_Float16)a.y;
    r[2] = (_Float16)a.z; r[3] = (_Float16)a.w;
    r[4] = (_Float16)b.x; r[5] = (_Float16)b.y;
    r[6] = (_Float16)b.z; r[7] = (_Float16)b.w;
    return r;
}

// ---------------------------------------------------------------------------
// Kernel 1: gate GEMM (K-split x8, disjoint partial buffers) FUSED with the
// f16 pre-conversion of q,k (direct) and v (LDS transpose -> [bh][d][s]).
// ---------------------------------------------------------------------------
__global__ __launch_bounds__(256, 4) void gates_kernel(
    const float* __restrict__ q, const float* __restrict__ k,
    const float* __restrict__ v, const float* __restrict__ Wi,
    const float* __restrict__ Wf, float* __restrict__ pre_i,
    float* __restrict__ pre_f, _Float16* __restrict__ qhg,
    _Float16* __restrict__ khg, _Float16* __restrict__ vtg)
{
    __shared__ __attribute__((aligned(16))) _Float16 xs[32 * 264];
    __shared__ __attribute__((aligned(16))) _Float16 wt[32 * 264];

    const int t    = threadIdx.x;
    const int w    = t >> 6, lane = t & 63, quad = lane >> 4, l15 = lane & 15;
    const int mw   = w & 1, nw = w >> 1;
    const int m0   = blockIdx.x * 32;
    const int by   = blockIdx.y;
    const int kbase = by * 768;
    const int bblk = m0 >> 10;           // batch index (constant per block)
    const int s0   = m0 & 1023;

    floatx4 acc = {0.f, 0.f, 0.f, 0.f};

    for (int c = 0; c < 3; ++c) {
        __syncthreads();
        const int e0   = kbase + c * 256;
        const int tsel = e0 >> 11;            // 0:q 1:k 2:v
        const int el0  = e0 & 2047;
        const float* xb = (tsel == 0) ? q : (tsel == 1) ? k : v;
        _Float16* fout = (tsel == 0) ? qhg : khg;   // direct f16 emit (q/k)
        #pragma unroll
        for (int i = 0; i < 4; ++i) {
            int g = t + i * 256;
            int row = g >> 5, grp = g & 31;
            half8 s8 = cvt8h(xb + (size_t)(m0 + row) * E_ + el0 + grp * 8);
            *(half8*)(&xs[row * 264 + grp * 8]) = s8;
            if (tsel < 2) {
                int el = el0 + grp * 8;
                int h  = el >> 7, d = el & 127;
                *(half8*)(fout + ((size_t)(bblk * NH_ + h) * S_ + s0 + row) * DH_ + d) = s8;
            }
        }
        {
            const int kk = t;
            const float* wiRow = Wi + (size_t)(e0 + kk) * NH_;
            const float* wfRow = Wf + (size_t)(e0 + kk) * NH_;
            float wif[16], wff[16];
            #pragma unroll
            for (int i4 = 0; i4 < 4; ++i4) {
                float4 a = *(const float4*)(wiRow + i4 * 4);
                wif[i4*4+0]=a.x; wif[i4*4+1]=a.y; wif[i4*4+2]=a.z; wif[i4*4+3]=a.w;
                float4 b = *(const float4*)(wfRow + i4 * 4);
                wff[i4*4+0]=b.x; wff[i4*4+1]=b.y; wff[i4*4+2]=b.z; wff[i4*4+3]=b.w;
            }
            #pragma unroll
            for (int hh = 0; hh < 16; ++hh) wt[hh * 264 + kk]        = (_Float16)wif[hh];
            #pragma unroll
            for (int hh = 0; hh < 16; ++hh) wt[(16 + hh) * 264 + kk] = (_Float16)wff[hh];
        }
        __syncthreads();
        // v chunk: emit transposed f16 [bh][d][s] from the staged LDS tile.
        if (tsel == 2) {
            const int col = t;                       // 0..255
            const int el  = el0 + col;
            const int h   = el >> 7, d = el & 127;
            _Float16 tmp[32];
            #pragma unroll
            for (int r = 0; r < 32; ++r) tmp[r] = xs[r * 264 + col];
            const size_t vo = ((size_t)(bblk * NH_ + h) * DH_ + d) * S_ + s0;
            #pragma unroll
            for (int i = 0; i < 4; ++i)
                *(half8*)(vtg + vo + i * 8) = *(half8*)(&tmp[i * 8]);
        }
        #pragma unroll
        for (int ks = 0; ks < 8; ++ks) {
            half8 af = *(const half8*)(&xs[(mw * 16 + l15) * 264 + ks * 32 + quad * 8]);
            half8 bw = *(const half8*)(&wt[(nw * 16 + l15) * 264 + ks * 32 + quad * 8]);
            acc = __builtin_amdgcn_mfma_f32_16x16x32_f16(af, bw, acc, 0, 0, 0);
        }
    }
    #pragma unroll
    for (int reg = 0; reg < 4; ++reg) {
        int m   = m0 + mw * 16 + quad * 4 + reg;
        int b   = m >> 10, s = m & 1023;
        int col = nw * 16 + l15;
        float vacc = acc[reg];
        if (col < 16)
            pre_i[((size_t)(by * 32 + b * NH_ + col)) * S_ + s] = vacc;
        else
            pre_f[((size_t)(by * 32 + b * NH_ + col - 16)) * S_ + s] = vacc;
    }
}

// ---------------------------------------------------------------------------
// Kernel 2: two-level block-parallel scan.
// ---------------------------------------------------------------------------
__global__ __launch_bounds__(1024, 1) void scan_kernel(
    const float* __restrict__ pre_i, const float* __restrict__ pre_f,
    float* __restrict__ Aj, float* __restrict__ Cq,
    float* __restrict__ NFo, const float* __restrict__ bi,
    const float* __restrict__ bfb)
{
    __shared__ float wsumF[16], wmaxA[16];
    const int bh   = blockIdx.x;
    const int h    = bh & 15;
    const int t    = threadIdx.x;        // = s
    const int lane = t & 63, wv = t >> 6;

    float igv = bi[h], x = bfb[h];
    #pragma unroll
    for (int y = 0; y < 8; ++y) {
        igv += pre_i[((size_t)(y * 32 + bh)) * S_ + t];
        x   += pre_f[((size_t)(y * 32 + bh)) * S_ + t];
    }
    float lfv = (x >= 0.f) ? -log1pf(__expf(-x)) : (x - log1pf(__expf(x)));

    float sc = lfv;
    #pragma unroll
    for (int off = 1; off < 64; off <<= 1) {
        float o = __shfl_up(sc, off);
        if (lane >= off) sc += o;
    }
    if (lane == 63) wsumF[wv] = sc;
    __syncthreads();
    float Foff = 0.f;
    for (int i = 0; i < wv; ++i) Foff += wsumF[i];
    float F = Foff + sc;
    float a = igv - F;

    float ms = a;
    #pragma unroll
    for (int off = 1; off < 64; off <<= 1) {
        float o = __shfl_up(ms, off);
        if (lane >= off) ms = fmaxf(ms, o);
    }
    if (lane == 63) wmaxA[wv] = ms;
    __syncthreads();
    float Moff = -3.0e38f;
    for (int i = 0; i < wv; ++i) Moff = fmaxf(Moff, wmaxA[i]);
    float M = fmaxf(Moff, ms);

    size_t o = (size_t)bh * S_ + t;
    Aj[o]  = a;
    Cq[o]  = -M;
    NFo[o] = expf(fminf(-(F + M), 80.f));
}

// ---------------------------------------------------------------------------
// Kernel 3: fused causal attention. 512 blocks (one 64-row q-tile each,
// 2 blocks/CU), 4 waves in a 2x2 arrangement over the 64x64 score tile:
// wave (mw,nw) owns rows mw*32..+32, score-cols nw*32..+32 (QK) and output
// dims nw*64..+64 (PV). Each bk/bv LDS read feeds 2 MFMAs (register blocking)
// -> 20 LDS reads / 32 MFMAs per wave-tile vs 34 before.
// P is col-split across waves, so PV needs b0 after P-writes; K-staging moves
// after b0 (Ks free), V-staging after b1; next tile's b0 closes the V hazard.
// ---------------------------------------------------------------------------
__global__ __launch_bounds__(256, 2) void attn_kernel(
    const _Float16* __restrict__ qh, const _Float16* __restrict__ kh,
    const _Float16* __restrict__ vtg, const float* __restrict__ Aj,
    const float* __restrict__ Cq, const float* __restrict__ NFi,
    const float* __restrict__ lnsc, float* __restrict__ out)
{
    __shared__ __attribute__((aligned(16))) _Float16 Ks[64 * 136];
    __shared__ __attribute__((aligned(16))) _Float16 Vt[128 * 72];
    __shared__ __attribute__((aligned(16))) _Float16 Pb[64 * 72];
    __shared__ float aj[64];
    __shared__ float lpart[2][2][32];    // [nw][mw][local row]
    __shared__ float spart[2][2][32];
    __shared__ float qpart[2][2][32];

    const int t    = threadIdx.x;
    const int w    = t >> 6, lane = t & 63, quad = lane >> 4, l15 = lane & 15;
    const int mw   = w & 1, nw = w >> 1;
    const int L    = blockIdx.x;
    int qi, bh;
    if (L < 256) { qi = L >> 5;                bh = L & 31; }
    else         { qi = 15 - ((L - 256) >> 5); bh = (L - 256) & 31; }
    const int b    = bh >> 4, h = bh & 15;
    const int q0   = qi * 64;
    const int krow = t >> 2, kd0 = (t & 3) * 32;   // K staging: 4 x b128
    const int vd   = t >> 1, vj0 = (t & 1) * 32;   // V staging: 4 x b128

    float ci_r[2][4], nfv_r[2][4];
    #pragma unroll
    for (int s = 0; s < 2; ++s)
        #pragma unroll
        for (int reg = 0; reg < 4; ++reg) {
            int rl = q0 + mw * 32 + s * 16 + quad * 4 + reg;
            ci_r[s][reg]  = Cq[(size_t)bh * S_ + rl];
            nfv_r[s][reg] = NFi[(size_t)bh * S_ + rl];
        }
    half8 aq[2][4];
    #pragma unroll
    for (int s = 0; s < 2; ++s) {
        const _Float16* qrow = qh + ((size_t)bh * S_ + q0 + mw * 32 + s * 16 + l15) * DH_;
        #pragma unroll
        for (int ks = 0; ks < 4; ++ks)
            aq[s][ks] = *(const half8*)(qrow + ks * 32 + quad * 8);
    }

    // ---- prefetch + stage tile 0 ----
    half8 kreg[4], vreg[4];
    float ajreg = 0.f;
    {
        const _Float16* kp = kh + ((size_t)bh * S_ + krow) * DH_ + kd0;
        const _Float16* vp = vtg + ((size_t)bh * DH_ + vd) * S_ + vj0;
        #pragma unroll
        for (int i = 0; i < 4; ++i) { kreg[i] = *(const half8*)(kp + i * 8);
                                      vreg[i] = *(const half8*)(vp + i * 8); }
    }
    if (t < 64) ajreg = Aj[(size_t)bh * S_ + t];

    #pragma unroll
    for (int i = 0; i < 4; ++i) {
        *(half8*)(&Ks[krow * 136 + kd0 + i * 8]) = kreg[i];
        *(half8*)(&Vt[vd * 72 + vj0 + i * 8])    = vreg[i];
    }
    if (t < 64) aj[t] = ajreg;
    __syncthreads();

    floatx4 acc_h[2][4];
    #pragma unroll
    for (int s = 0; s < 2; ++s)
        #pragma unroll
        for (int i = 0; i < 4; ++i) acc_h[s][i] = (floatx4){0.f, 0.f, 0.f, 0.f};
    float lrun[2][4] = {{0.f, 0.f, 0.f, 0.f}, {0.f, 0.f, 0.f, 0.f}};
    const float rscale = 0.08838834764831845f;   // 1/sqrt(128)

    for (int kt = 0; kt <= qi; ++kt) {
        if (kt < qi) {
            const int j0n = (kt + 1) * 64;
            const _Float16* kp = kh + ((size_t)bh * S_ + j0n + krow) * DH_ + kd0;
            const _Float16* vp = vtg + ((size_t)bh * DH_ + vd) * S_ + j0n + vj0;
            #pragma unroll
            for (int i = 0; i < 4; ++i) { kreg[i] = *(const half8*)(kp + i * 8);
                                          vreg[i] = *(const half8*)(vp + i * 8); }
            if (t < 64) ajreg = Aj[(size_t)bh * S_ + j0n + t];
        }

        const bool diag = (kt == qi);
        // ---- QK: wave computes 32x32 sub-tile; 8 bk reads feed 16 MFMAs ----
        floatx4 sacc[2][2];
        #pragma unroll
        for (int s = 0; s < 2; ++s)
            #pragma unroll
            for (int n = 0; n < 2; ++n) sacc[s][n] = (floatx4){0.f, 0.f, 0.f, 0.f};
        if (!(diag && mw == 0 && nw == 1)) {     // fully-masked wave on diag
            __builtin_amdgcn_s_setprio(1);
            #pragma unroll
            for (int ks = 0; ks < 4; ++ks) {
                #pragma unroll
                for (int n = 0; n < 2; ++n) {
                    half8 bk = *(const half8*)(&Ks[(nw * 32 + n * 16 + l15) * 136 + ks * 32 + quad * 8]);
                    sacc[0][n] = __builtin_amdgcn_mfma_f32_16x16x32_f16(aq[0][ks], bk, sacc[0][n], 0, 0, 0);
                    sacc[1][n] = __builtin_amdgcn_mfma_f32_16x16x32_f16(aq[1][ks], bk, sacc[1][n], 0, 0, 0);
                }
            }
            __builtin_amdgcn_s_setprio(0);
        }
        // ---- P compute + write (wave's 32x32 quadrant of Pb) ----
        #pragma unroll
        for (int n = 0; n < 2; ++n) {
            int jl = nw * 32 + n * 16 + l15;
            float a_j = aj[jl];
            #pragma unroll
            for (int s = 0; s < 2; ++s) {
                #pragma unroll
                for (int reg = 0; reg < 4; ++reg) {
                    int rloc = mw * 32 + s * 16 + quad * 4 + reg;
                    float p = 0.f;
                    if (!diag || (jl <= rloc))
                        p = sacc[s][n][reg] * rscale * __expf(fminf(ci_r[s][reg] + a_j, 0.f));
                    lrun[s][reg] += p;
                    Pb[rloc * 72 + jl] = (_Float16)p;
                }
            }
        }
        __syncthreads();   // b0: P complete; Ks reads complete -> Ks free

        if (kt < qi) {     // K + aj staging overlaps PV phase
            #pragma unroll
            for (int i = 0; i < 4; ++i)
                *(half8*)(&Ks[krow * 136 + kd0 + i * 8]) = kreg[i];
            if (t < 64) aj[t] = ajreg;
        }
        // ---- PV: 4 ap + 8 bv reads feed 16 MFMAs ----
        __builtin_amdgcn_s_setprio(1);
        #pragma unroll
        for (int ks2 = 0; ks2 < 2; ++ks2) {
            half8 ap0 = *(const half8*)(&Pb[(mw * 32 + l15) * 72 + ks2 * 32 + quad * 8]);
            half8 ap1 = *(const half8*)(&Pb[(mw * 32 + 16 + l15) * 72 + ks2 * 32 + quad * 8]);
            #pragma unroll
            for (int n = 0; n < 4; ++n) {
                half8 bv = *(const half8*)(&Vt[(nw * 64 + n * 16 + l15) * 72 + ks2 * 32 + quad * 8]);
                acc_h[0][n] = __builtin_amdgcn_mfma_f32_16x16x32_f16(ap0, bv, acc_h[0][n], 0, 0, 0);
                acc_h[1][n] = __builtin_amdgcn_mfma_f32_16x16x32_f16(ap1, bv, acc_h[1][n], 0, 0, 0);
            }
        }
        __builtin_amdgcn_s_setprio(0);
        __syncthreads();   // b1: PV reads (Vt, Pb) complete

        if (kt < qi) {     // V staging; next tile's b0 closes write->read hazard
            #pragma unroll
            for (int i = 0; i < 4; ++i)
                *(half8*)(&Vt[vd * 72 + vj0 + i * 8]) = vreg[i];
        }
    }

    // ---- epilogue: cross-wave (nw) combine of row-sum, then LayerNorm ----
    #pragma unroll
    for (int s = 0; s < 2; ++s)
        #pragma unroll
        for (int reg = 0; reg < 4; ++reg) {
            float l = lrun[s][reg];
            l += __shfl_xor(l, 1); l += __shfl_xor(l, 2);
            l += __shfl_xor(l, 4); l += __shfl_xor(l, 8);
            if (l15 == 0) lpart[nw][mw][s * 16 + quad * 4 + reg] = l;
        }
    __syncthreads();
    float inv_r[2][4];
    #pragma unroll
    for (int s = 0; s < 2; ++s)
        #pragma unroll
        for (int reg = 0; reg < 4; ++reg) {
            int rr = s * 16 + quad * 4 + reg;
            float ltot = lpart[0][mw][rr] + lpart[1][mw][rr];
            inv_r[s][reg] = 1.f / (fmaxf(fabsf(ltot), nfv_r[s][reg]) + EPS_);
        }
    #pragma unroll
    for (int s = 0; s < 2; ++s)
        #pragma unroll
        for (int reg = 0; reg < 4; ++reg) {
            float sum = 0.f, sq = 0.f;
            #pragma unroll
            for (int n = 0; n < 4; ++n) {
                float x = acc_h[s][n][reg] * inv_r[s][reg];
                sum += x; sq += x * x;
            }
            sum += __shfl_xor(sum, 1); sq += __shfl_xor(sq, 1);
            sum += __shfl_xor(sum, 2); sq += __shfl_xor(sq, 2);
            sum += __shfl_xor(sum, 4); sq += __shfl_xor(sq, 4);
            sum += __shfl_xor(sum, 8); sq += __shfl_xor(sq, 8);
            if (l15 == 0) {
                spart[nw][mw][s * 16 + quad * 4 + reg] = sum;
                qpart[nw][mw][s * 16 + quad * 4 + reg] = sq;
            }
        }
    __syncthreads();
    #pragma unroll
    for (int s = 0; s < 2; ++s)
        #pragma unroll
        for (int reg = 0; reg < 4; ++reg) {
            int rr   = s * 16 + quad * 4 + reg;
            float sum = spart[0][mw][rr] + spart[1][mw][rr];
            float sq  = qpart[0][mw][rr] + qpart[1][mw][rr];
            float mean = sum * (1.f / 128.f);
            float var  = fmaxf(sq * (1.f / 128.f) - mean * mean, 0.f);
            float rstd = rsqrtf(var + EPS_);
            int rl = q0 + mw * 32 + rr;
            size_t orow = ((size_t)b * S_ + rl) * E_ + h * DH_;
            #pragma unroll
            for (int n = 0; n < 4; ++n) {
                int d = nw * 64 + n * 16 + l15;
                out[orow + d] = (acc_h[s][n][reg] * inv_r[s][reg] - mean) * rstd * lnsc[h * DH_ + d];
            }
        }
}

// ---------------------------------------------------------------------------
extern "C" void kernel_launch(void* const* d_in, const int* in_sizes, int n_in,
                              void* d_out, int out_size, void* d_ws, size_t ws_size,
                              hipStream_t stream)
{
    const float* q    = (const float*)d_in[0];
    const float* k    = (const float*)d_in[1];
    const float* v    = (const float*)d_in[2];
    const float* Wi   = (const float*)d_in[3];
    const float* bi   = (const float*)d_in[4];
    const float* Wf   = (const float*)d_in[5];
    const float* bfb  = (const float*)d_in[6];
    const float* lnsc = (const float*)d_in[7];
    float* out        = (float*)d_out;

    const int NS  = B_ * NH_ * S_;       // 32768
    float* pre_i = (float*)d_ws;         // [8][32][1024] partials
    float* pre_f = pre_i + 8 * NS;
    float* Aj    = pre_f + 8 * NS;
    float* Cq    = Aj + NS;
    float* NFa   = Cq + NS;
    _Float16* qh  = (_Float16*)(NFa + NS);          // [32][1024][128] f16
    _Float16* kh  = qh + (size_t)32 * S_ * DH_;
    _Float16* vtg = kh + (size_t)32 * S_ * DH_;     // [32][128][1024] f16

    gates_kernel<<<dim3(64, 8), 256, 0, stream>>>(q, k, v, Wi, Wf, pre_i, pre_f,
                                                  qh, kh, vtg);
    scan_kernel<<<dim3(32), 1024, 0, stream>>>(pre_i, pre_f, Aj, Cq, NFa, bi, bfb);
    attn_kernel<<<dim3(512), 256, 0, stream>>>(qh, kh, vtg, Aj, Cq, NFa, lnsc, out);
}